// Round 3
// baseline (1199.903 us; speedup 1.0000x reference)
//
#include <hip/hip_runtime.h>

#define NB 48
#define NT 5000
#define NF 161
#define NROWS (NB * NT)          // 240000
#define MAGN  (NROWS * NF)       // 38640000
#define RPB  20                  // rows per block (chunk)
#define CPB  (NT / RPB)          // 250 chunks per batch
#define NBLK (NB * CPB)          // 12000 blocks
#define TILE (RPB * NF)          // 3220 floats per tile
#define TILE4 (TILE / 4)         // 805 float4
#define A0   0.121576654590569288f   // 0.9^20, local affine A for every chunk

// flags in the high 32 bits of the packed state word
#define FLG_AGG 1u
#define FLG_INC 2u
// anything else (including the harness 0xAAAAAAAA poison) == NOT_READY

__global__ __launch_bounds__(256) void fused_kernel(const float* __restrict__ mag,
                                                    float* __restrict__ out,
                                                    float* __restrict__ gout,
                                                    unsigned long long* __restrict__ state) {
    __shared__ float sx[TILE];       // 12880 B tile stage
    __shared__ float sxr[RPB];       // x per row
    __shared__ float sg[RPB];        // gain per row
    __shared__ float s_gprev;        // end-gain of previous chunk

    const int tid  = threadIdx.x;
    const int wave = tid >> 6;
    const int lane = tid & 63;
    const int blk  = blockIdx.x;
    const int b    = blk / CPB;
    const int c    = blk - b * CPB;
    const size_t base = (size_t)blk * TILE;   // == (b*NT + c*RPB)*NF

    // ---- stage tile global -> LDS, dense float4 ----
    const float4* g4 = (const float4*)(mag + base);
    float4* s4 = (float4*)sx;
    for (int i = tid; i < TILE4; i += 256) s4[i] = g4[i];
    __syncthreads();

    // ---- per-row weighted power + sqrt: wave w reduces rows 5w..5w+4 ----
#pragma unroll
    for (int i = 0; i < 5; ++i) {
        const int r = wave * 5 + i;
        const float* rp = sx + r * NF;
        float sum = 0.f;
#pragma unroll
        for (int k0 = 0; k0 < NF; k0 += 64) {
            int k = k0 + lane;
            if (k < NF) {
                float v = rp[k];
                float w = (k == 0 || k == NF - 1) ? 1.f : 2.f;
                sum += w * v * v;
            }
        }
#pragma unroll
        for (int off = 32; off > 0; off >>= 1)
            sum += __shfl_down(sum, off, 64);
        if (lane == 0) sxr[r] = sqrtf(sum / 320.f);
    }
    __syncthreads();

    // ---- publish local result; lookback; gains ----
    if (c == 0) {
        if (tid == 0) {
            float g = sxr[0];                 // frame 0 passes through
            sg[0] = g;
#pragma unroll
            for (int t = 1; t < RPB; ++t) { g = 0.9f * g + 0.1f * sxr[t]; sg[t] = g; }
            __hip_atomic_store(&state[blk],
                ((unsigned long long)FLG_INC << 32) | (unsigned long long)__float_as_uint(g),
                __ATOMIC_RELEASE, __HIP_MEMORY_SCOPE_AGENT);
        }
    } else {
        float Bl = 0.f;                       // local affine offset (A is A0)
        if (tid == 0) {
#pragma unroll
            for (int t = 0; t < RPB; ++t) Bl = 0.9f * Bl + 0.1f * sxr[t];
            __hip_atomic_store(&state[blk],
                ((unsigned long long)FLG_AGG << 32) | (unsigned long long)__float_as_uint(Bl),
                __ATOMIC_RELEASE, __HIP_MEMORY_SCOPE_AGENT);
        }
        if (wave == 0) {
            // wave-parallel decoupled lookback, 64 predecessors per round
            const float a0p = powf(A0, (float)lane);    // A0^lane
            float Aacc = 1.f, Bacc = 0.f;
            int j0 = c - 1;
            const unsigned long long* stb = state + (size_t)b * CPB;
            float gprev;
            for (;;) {
                const int j = j0 - lane;
                unsigned flag = 0u;
                float pay = 0.f;
                if (j >= 0) {
                    unsigned long long pk = __hip_atomic_load(&stb[j],
                        __ATOMIC_ACQUIRE, __HIP_MEMORY_SCOPE_AGENT);
                    unsigned f = (unsigned)(pk >> 32);
                    if (f == FLG_AGG || f == FLG_INC) flag = f;
                    pay = __uint_as_float((unsigned)pk);
                }
                const unsigned long long nonagg = __ballot(flag != FLG_AGG);
                const int P = (nonagg == 0ull) ? 64 : (__ffsll((unsigned long long)nonagg) - 1);
                // S = sum_{i<P} A0^i * B_i  (butterfly: every lane gets S)
                float term = (lane < P) ? a0p * pay : 0.f;
#pragma unroll
                for (int off = 32; off > 0; off >>= 1)
                    term += __shfl_xor(term, off, 64);
                if (P < 64) {
                    const unsigned fP = __shfl(flag, P, 64);
                    if (fP == FLG_INC) {
                        const float vP  = __shfl(pay, P, 64);
                        const float aP  = __shfl(a0p, P, 64);   // A0^P
                        gprev = Bacc + Aacc * (term + aP * vP);
                        break;
                    }
                    // NOT_READY at P: consume the aggregates before it, retry
                    Bacc += Aacc * term;
                    Aacc *= __shfl(a0p, P, 64);
                    j0 -= P;                   // P may be 0 -> pure spin
                } else {
                    Bacc += Aacc * term;
                    Aacc *= __shfl(a0p, 63, 64) * A0;           // A0^64
                    j0 -= 64;
                }
            }
            if (lane == 0) {
                // publish inclusive ASAP to unblock successors
                const float gend = A0 * gprev + Bl;
                __hip_atomic_store(&state[blk],
                    ((unsigned long long)FLG_INC << 32) | (unsigned long long)__float_as_uint(gend),
                    __ATOMIC_RELEASE, __HIP_MEMORY_SCOPE_AGENT);
                s_gprev = gprev;
            }
        }
        __syncthreads();
        if (tid == 0) {
            float g = s_gprev;
#pragma unroll
            for (int t = 0; t < RPB; ++t) { g = 0.9f * g + 0.1f * sxr[t]; sg[t] = g; }
        }
    }
    __syncthreads();

    // ---- divide tile out of LDS, write new_mag ----
    float4* o4 = (float4*)(out + base);
    for (int i = tid; i < TILE4; i += 256) {
        float4 m = s4[i];
        const int e  = i * 4;
        const int r0 = e / NF;                 // block-local row 0..19
        const int r3 = (e + 3) / NF;
        const float ga = __builtin_amdgcn_rcpf(sg[r0] + 0.001f);
        const float gb = __builtin_amdgcn_rcpf(sg[r3] + 0.001f);
        const int lim = (r0 + 1) * NF;
        float4 o;
        o.x = m.x * ga;
        o.y = m.y * ((e + 1 < lim) ? ga : gb);
        o.z = m.z * ((e + 2 < lim) ? ga : gb);
        o.w = m.w * gb;
        o4[i] = o;
    }
    // ---- gains out ----
    if (tid < RPB) gout[(size_t)blk * RPB + tid] = sg[tid];
}

extern "C" void kernel_launch(void* const* d_in, const int* in_sizes, int n_in,
                              void* d_out, int out_size, void* d_ws, size_t ws_size,
                              hipStream_t stream) {
    const float* mag = (const float*)d_in[0];
    float* out  = (float*)d_out;
    float* gout = out + (size_t)MAGN;          // slice_gain region [B*T]
    unsigned long long* state = (unsigned long long*)d_ws;  // 12000*8 B; 0xAA poison == NOT_READY

    fused_kernel<<<NBLK, 256, 0, stream>>>(mag, out, gout, state);
}

// Round 4
// 442.306 us; speedup vs baseline: 2.7128x; 2.7128x over previous
//
#include <hip/hip_runtime.h>

#define NB 48
#define NT 5000
#define NF 161
#define NROWS (NB * NT)          // 240000
#define MAGN  (NROWS * NF)       // 38640000
#define RPB  40                  // rows per block (chunk)
#define CPB  (NT / RPB)          // 125 chunks per batch
#define NBLK (NB * CPB)          // 6000 blocks
#define TILE (RPB * NF)          // 6440 floats per tile
#define TILE4 (TILE / 4)         // 1610 float4
#define A0   0.0147808829414346f // 0.9^40 — chunk affine A; A0^19 < fp32 denorm

#define FLG_AGG 1u
// any other high-word (incl. harness 0xAAAAAAAA poison) == NOT_READY

__global__ __launch_bounds__(256) void fused_kernel(const float* __restrict__ mag,
                                                    float* __restrict__ out,
                                                    float* __restrict__ gout,
                                                    unsigned long long* __restrict__ state) {
    __shared__ float sx[TILE];       // 25760 B tile stage
    __shared__ float sxr[RPB];       // x per row
    __shared__ float sg[RPB];        // gain per row
    __shared__ float s_gprev;

    const int tid  = threadIdx.x;
    const int wave = tid >> 6;
    const int lane = tid & 63;
    const int blk  = blockIdx.x;
    const int b    = blk / CPB;
    const int c    = blk - b * CPB;
    const size_t base = (size_t)blk * TILE;

    // ---- stage tile global -> LDS, dense float4 ----
    const float4* g4 = (const float4*)(mag + base);
    float4* s4 = (float4*)sx;
    for (int i = tid; i < TILE4; i += 256) s4[i] = g4[i];
    __syncthreads();

    // ---- per-row weighted power + sqrt: wave w reduces rows 10w..10w+9 ----
#pragma unroll
    for (int i = 0; i < RPB / 4; ++i) {
        const int r = wave * (RPB / 4) + i;
        const float* rp = sx + r * NF;
        float sum = 0.f;
#pragma unroll
        for (int k0 = 0; k0 < NF; k0 += 64) {
            int k = k0 + lane;
            if (k < NF) {
                float v = rp[k];
                float w = (k == 0 || k == NF - 1) ? 1.f : 2.f;
                sum += w * v * v;
            }
        }
#pragma unroll
        for (int off = 32; off > 0; off >>= 1)
            sum += __shfl_down(sum, off, 64);
        if (lane == 0) sxr[r] = sqrtf(sum / 320.f);
    }
    __syncthreads();

    // ---- publish aggregate; truncated 64-wide lookback; per-row gains ----
    if (c == 0) {
        if (tid == 0) {
            float g = sxr[0];                 // frame 0 passes through
            sg[0] = g;
#pragma unroll
            for (int t = 1; t < RPB; ++t) { g = 0.9f * g + 0.1f * sxr[t]; sg[t] = g; }
            // payload = end gain; coefficient A0^(c-1) in successors' sums is exact
            __hip_atomic_store(&state[blk],
                ((unsigned long long)FLG_AGG << 32) | (unsigned long long)__float_as_uint(g),
                __ATOMIC_RELEASE, __HIP_MEMORY_SCOPE_AGENT);
        }
    } else {
        if (tid == 0) {
            float Bl = 0.f;                   // local affine offset (A is A0)
#pragma unroll
            for (int t = 0; t < RPB; ++t) Bl = 0.9f * Bl + 0.1f * sxr[t];
            __hip_atomic_store(&state[blk],
                ((unsigned long long)FLG_AGG << 32) | (unsigned long long)__float_as_uint(Bl),
                __ATOMIC_RELEASE, __HIP_MEMORY_SCOPE_AGENT);
        }
        if (wave == 0) {
            // g_prev = sum_{i=0..63} A0^i * pay(c-1-i); terms beyond window are
            // exactly 0 in fp32 (A0^63 ~ 1e-115). Only nearby blocks are awaited.
            const unsigned long long* stb = state + (size_t)b * CPB;
            const int j = c - 1 - lane;
            float pay = 0.f;
            if (j >= 0) {
                unsigned long long pk;
                while ((unsigned)((pk = __hip_atomic_load(&stb[j],
                            __ATOMIC_ACQUIRE, __HIP_MEMORY_SCOPE_AGENT)) >> 32) != FLG_AGG)
                    __builtin_amdgcn_s_sleep(2);   // throttle coherence traffic
                pay = __uint_as_float((unsigned)pk);
            }
            float term = (j >= 0) ? powf(A0, (float)lane) * pay : 0.f;
#pragma unroll
            for (int off = 32; off > 0; off >>= 1)
                term += __shfl_xor(term, off, 64);
            if (lane == 0) s_gprev = term;
        }
        __syncthreads();
        if (tid == 0) {
            float g = s_gprev;
#pragma unroll
            for (int t = 0; t < RPB; ++t) { g = 0.9f * g + 0.1f * sxr[t]; sg[t] = g; }
        }
    }
    __syncthreads();

    // ---- divide tile out of LDS, write new_mag ----
    float4* o4 = (float4*)(out + base);
    for (int i = tid; i < TILE4; i += 256) {
        float4 m = s4[i];
        const int e  = i * 4;
        const int r0 = e / NF;                 // block-local row
        const int r3 = (e + 3) / NF;
        const float ga = __builtin_amdgcn_rcpf(sg[r0] + 0.001f);
        const float gb = __builtin_amdgcn_rcpf(sg[r3] + 0.001f);
        const int lim = (r0 + 1) * NF;
        float4 o;
        o.x = m.x * ga;
        o.y = m.y * ((e + 1 < lim) ? ga : gb);
        o.z = m.z * ((e + 2 < lim) ? ga : gb);
        o.w = m.w * gb;
        o4[i] = o;
    }
    // ---- gains out ----
    if (tid < RPB) gout[(size_t)blk * RPB + tid] = sg[tid];
}

extern "C" void kernel_launch(void* const* d_in, const int* in_sizes, int n_in,
                              void* d_out, int out_size, void* d_ws, size_t ws_size,
                              hipStream_t stream) {
    const float* mag = (const float*)d_in[0];
    float* out  = (float*)d_out;
    float* gout = out + (size_t)MAGN;          // slice_gain region [B*T]
    unsigned long long* state = (unsigned long long*)d_ws;  // NBLK*8 B; 0xAA poison == NOT_READY

    fused_kernel<<<NBLK, 256, 0, stream>>>(mag, out, gout, state);
}